// Round 1
// baseline (363.196 us; speedup 1.0000x reference)
//
#include <hip/hip_runtime.h>
#include <math.h>

#define NB 4096
#define NE 64
#define ND 256
#define ROWS_PER_BLOCK 4
#define NBLOCKS (NB / ROWS_PER_BLOCK)

__global__ __launch_bounds__(256) void acc_kernel(
    const float* __restrict__ pred,
    const float* __restrict__ ev,
    const int* __restrict__ em,
    int* __restrict__ out)
{
    __shared__ float dist2[NE];
    __shared__ int lcnt[24];
    const int tid  = threadIdx.x;
    const int wave = tid >> 6;   // 0..3
    const int lane = tid & 63;

    if (tid < 24) lcnt[tid] = 0;
    __syncthreads();

    for (int j = 0; j < ROWS_PER_BLOCK; ++j) {
        const int b = blockIdx.x * ROWS_PER_BLOCK + j;

        // predicted[b, lane*4 .. lane*4+3]
        const float4 p = ((const float4*)pred)[(size_t)b * (ND / 4) + lane];
        const float4* evb = (const float4*)ev + (size_t)b * NE * (ND / 4);

        // each wave computes 16 entity distances; lane i loads 16B coalesced
        #pragma unroll
        for (int i = 0; i < 16; ++i) {
            const int e = wave * 16 + i;
            const float4 v = evb[e * (ND / 4) + lane];
            const float dx = v.x - p.x, dy = v.y - p.y;
            const float dz = v.z - p.z, dw = v.w - p.w;
            float s = dx * dx + dy * dy + dz * dz + dw * dw;
            #pragma unroll
            for (int off = 32; off > 0; off >>= 1)
                s += __shfl_xor(s, off, 64);
            if (lane == 0) dist2[e] = s;   // squared distance of entity e
        }
        __syncthreads();

        if (wave == 0) {
            // lane <-> entity
            const bool m = em[((size_t)b * NE + lane) * 2] != 0;
            const unsigned long long bm = __ballot(m);
            const bool known = (bm & 1ull) != 0ull;
            const bool hn    = (bm & (bm - 1ull)) != 0ull;   // >= 2 masked
            const int  first = __ffsll(bm) - 1;              // first masked entity
            const bool neg   = m && (lane != first);

            float mn2 = neg ? dist2[lane] : INFINITY;
            #pragma unroll
            for (int off = 32; off > 0; off >>= 1)
                mn2 = fminf(mn2, __shfl_xor(mn2, off, 64));

            if (lane == 0) {
                const float pos2 = dist2[0];
                const int idx = (known ? 2 : 0) + (hn ? 1 : 0);
                lcnt[idx] += 1;
                const float t2[5] = {0.25f, 1.0f, 2.25f, 4.0f, 9.0f};
                #pragma unroll
                for (int t = 0; t < 5; ++t) {
                    bool flag = false;
                    if (known && !hn)      flag = t2[t] < pos2;
                    else if (!known && hn) flag = mn2 < t2[t];
                    else if (known && hn)  flag = fminf(mn2, t2[t]) < pos2;
                    if (flag) lcnt[4 + t * 4 + idx] += 1;
                }
            }
        }
        __syncthreads();   // protect dist2 before next row overwrites
    }

    if (tid < 24 && lcnt[tid] != 0) atomicAdd(&out[tid], lcnt[tid]);
}

extern "C" void kernel_launch(void* const* d_in, const int* in_sizes, int n_in,
                              void* d_out, int out_size, void* d_ws, size_t ws_size,
                              hipStream_t stream) {
    const float* pred = (const float*)d_in[0];   // (4096, 256) fp32
    const float* ev   = (const float*)d_in[1];   // (4096, 64, 256) fp32
    const int*   em   = (const int*)d_in[2];     // (4096, 64, 2) int32
    int* out = (int*)d_out;                      // 24 int32 counters

    // d_out is poisoned 0xAA before every timed launch; we accumulate with
    // atomics, so zero it on-stream first (hipMemsetAsync is capture-legal).
    hipMemsetAsync(out, 0, out_size * sizeof(int), stream);
    acc_kernel<<<NBLOCKS, 256, 0, stream>>>(pred, ev, em, out);
}

// Round 2
// 362.070 us; speedup vs baseline: 1.0031x; 1.0031x over previous
//
#include <hip/hip_runtime.h>
#include <math.h>

#define NB 4096
#define NE 64
#define ND4 64              // 256 dims / 4 floats
#define ROWS_PER_BLOCK 4
#define NBLOCKS (NB / ROWS_PER_BLOCK)

__global__ __launch_bounds__(256) void acc_kernel(
    const float* __restrict__ pred,
    const float* __restrict__ ev,
    const int* __restrict__ em,
    int* __restrict__ out)
{
    __shared__ float dist2[NE];
    __shared__ int lcnt[24];
    const int tid  = threadIdx.x;
    const int wave = tid >> 6;      // 0..3
    const int lane = tid & 63;
    const int eg   = lane >> 4;     // 0..3 : entity subgroup within wave
    const int dg   = lane & 15;     // 0..15: dim group (16 floats each)

    if (tid < 24) lcnt[tid] = 0;
    // no barrier needed yet: first lcnt increment happens after the first
    // __syncthreads below

    for (int j = 0; j < ROWS_PER_BLOCK; ++j) {
        const int b = blockIdx.x * ROWS_PER_BLOCK + j;
        const float4* predb = (const float4*)pred + (size_t)b * ND4;
        const float4* evb   = (const float4*)ev   + (size_t)b * NE * ND4;

        // each lane caches its 16 floats of predicted (4 float4, stride 16)
        float4 pl[4];
        #pragma unroll
        for (int c = 0; c < 4; ++c) pl[c] = predb[c * 16 + dg];

        // wave handles entities [wave*16, wave*16+16) in 4 passes of 4
        #pragma unroll
        for (int p = 0; p < 4; ++p) {
            const int e = wave * 16 + p * 4 + eg;
            const float4* ee = evb + (size_t)e * ND4;
            float s = 0.f;
            #pragma unroll
            for (int c = 0; c < 4; ++c) {
                const float4 v = ee[c * 16 + dg];
                const float dx = v.x - pl[c].x, dy = v.y - pl[c].y;
                const float dz = v.z - pl[c].z, dw = v.w - pl[c].w;
                s += dx * dx + dy * dy + dz * dz + dw * dw;
            }
            // reduce over the 16 dim-group lanes (xor within low 4 lane bits)
            #pragma unroll
            for (int off = 1; off < 16; off <<= 1)
                s += __shfl_xor(s, off, 64);
            if (dg == 0) dist2[e] = s;
        }
        __syncthreads();

        if (wave == 0) {
            // lane <-> entity
            const bool m = em[((size_t)b * NE + lane) * 2] != 0;
            const unsigned long long bm = __ballot(m);
            const bool known = (bm & 1ull) != 0ull;
            const bool hn    = (bm & (bm - 1ull)) != 0ull;   // >= 2 masked
            const int  first = __ffsll(bm) - 1;              // first masked entity
            const bool neg   = m && (lane != first);

            float mn2 = neg ? dist2[lane] : INFINITY;
            #pragma unroll
            for (int off = 32; off > 0; off >>= 1)
                mn2 = fminf(mn2, __shfl_xor(mn2, off, 64));

            if (lane == 0) {
                const float pos2 = dist2[0];
                const int idx = (known ? 2 : 0) + (hn ? 1 : 0);
                lcnt[idx] += 1;
                const float t2[5] = {0.25f, 1.0f, 2.25f, 4.0f, 9.0f};
                #pragma unroll
                for (int t = 0; t < 5; ++t) {
                    bool flag = false;
                    if (known && !hn)      flag = t2[t] < pos2;
                    else if (!known && hn) flag = mn2 < t2[t];
                    else if (known && hn)  flag = fminf(mn2, t2[t]) < pos2;
                    if (flag) lcnt[4 + t * 4 + idx] += 1;
                }
            }
        }
        __syncthreads();   // protect dist2/lcnt before next row
    }

    if (tid < 24 && lcnt[tid] != 0) atomicAdd(&out[tid], lcnt[tid]);
}

extern "C" void kernel_launch(void* const* d_in, const int* in_sizes, int n_in,
                              void* d_out, int out_size, void* d_ws, size_t ws_size,
                              hipStream_t stream) {
    const float* pred = (const float*)d_in[0];   // (4096, 256) fp32
    const float* ev   = (const float*)d_in[1];   // (4096, 64, 256) fp32
    const int*   em   = (const int*)d_in[2];     // (4096, 64, 2) int32
    int* out = (int*)d_out;                      // 24 int32 counters

    hipMemsetAsync(out, 0, out_size * sizeof(int), stream);
    acc_kernel<<<NBLOCKS, 256, 0, stream>>>(pred, ev, em, out);
}

// Round 3
// 345.856 us; speedup vs baseline: 1.0501x; 1.0469x over previous
//
#include <hip/hip_runtime.h>
#include <math.h>

#define NB 4096
#define NE 64
#define ND4 64              // 256 dims / 4 floats
#define RPB 2               // rows per block
#define NBLOCKS (NB / RPB)  // 2048 blocks -> 8 blocks/CU, 32 waves/CU

__global__ __launch_bounds__(256) void acc_kernel(
    const float* __restrict__ pred,
    const float* __restrict__ ev,
    const int* __restrict__ em,
    int* __restrict__ out)
{
    __shared__ float wmin[RPB][4];   // per-wave min_neg^2
    __shared__ float wpos[RPB];      // pos^2 (valid only when known)
    __shared__ int   kn[RPB], hn[RPB];
    __shared__ int   lcnt[24];

    const int tid  = threadIdx.x;
    const int wave = tid >> 6;
    const int lane = tid & 63;

    if (tid < 24) lcnt[tid] = 0;

    for (int j = 0; j < RPB; ++j) {
        const int b = blockIdx.x * RPB + j;
        const float4  p   = ((const float4*)pred)[(size_t)b * ND4 + lane];
        const float4* evb = (const float4*)ev + (size_t)b * NE * ND4;

        // mask bit per entity (lane <-> entity); ballot -> wave-uniform mask
        const bool m = em[((size_t)b * NE + lane) * 2] != 0;
        const unsigned long long bm = __ballot(m);
        const bool known = (bm & 1ull) != 0ull;
        const unsigned long long nm = bm & (bm - 1ull); // masked minus first masked

        // wave w handles every 4th set bit of nm starting at rank w
        unsigned long long mynm = nm;
        for (int i = 0; i < wave && mynm; ++i) mynm &= mynm - 1ull;

        float mn2 = INFINITY;
        while (mynm) {
            const int e = (int)__ffsll(mynm) - 1;       // wave-uniform
            const float4 v = evb[(size_t)e * ND4 + lane]; // 1 KB coalesced
            const float dx = v.x - p.x, dy = v.y - p.y;
            const float dz = v.z - p.z, dw = v.w - p.w;
            float s = dx*dx + dy*dy + dz*dz + dw*dw;
            #pragma unroll
            for (int off = 32; off > 0; off >>= 1)
                s += __shfl_xor(s, off, 64);
            mn2 = fminf(mn2, s);
            #pragma unroll
            for (int i = 0; i < 4; ++i) mynm &= mynm - 1ull; // skip to next rank+4
        }
        if (lane == 0) wmin[j][wave] = mn2;

        // entity-0 distance only when known (pos unused otherwise)
        if (wave == 0) {
            if (known) {
                const float4 v = evb[lane];
                const float dx = v.x - p.x, dy = v.y - p.y;
                const float dz = v.z - p.z, dw = v.w - p.w;
                float s = dx*dx + dy*dy + dz*dz + dw*dw;
                #pragma unroll
                for (int off = 32; off > 0; off >>= 1)
                    s += __shfl_xor(s, off, 64);
                if (lane == 0) wpos[j] = s;
            }
            if (lane == 0) { kn[j] = known; hn[j] = (nm != 0ull); }
        }
    }
    __syncthreads();

    // finalize: thread j handles row j
    if (tid < RPB) {
        const int j = tid;
        const bool known = kn[j] != 0;
        const bool hneg  = hn[j] != 0;
        const float mn2  = fminf(fminf(wmin[j][0], wmin[j][1]),
                                 fminf(wmin[j][2], wmin[j][3]));
        const float pos2 = known ? wpos[j] : 0.f;
        const int idx = (known ? 2 : 0) + (hneg ? 1 : 0);
        atomicAdd(&lcnt[idx], 1);
        const float t2[5] = {0.25f, 1.0f, 2.25f, 4.0f, 9.0f};
        #pragma unroll
        for (int t = 0; t < 5; ++t) {
            bool flag = false;
            if (known && !hneg)      flag = t2[t] < pos2;
            else if (!known && hneg) flag = mn2 < t2[t];
            else if (known && hneg)  flag = fminf(mn2, t2[t]) < pos2;
            if (flag) atomicAdd(&lcnt[4 + t * 4 + idx], 1);
        }
    }
    __syncthreads();

    if (tid < 24 && lcnt[tid] != 0) atomicAdd(&out[tid], lcnt[tid]);
}

extern "C" void kernel_launch(void* const* d_in, const int* in_sizes, int n_in,
                              void* d_out, int out_size, void* d_ws, size_t ws_size,
                              hipStream_t stream) {
    const float* pred = (const float*)d_in[0];   // (4096, 256) fp32
    const float* ev   = (const float*)d_in[1];   // (4096, 64, 256) fp32
    const int*   em   = (const int*)d_in[2];     // (4096, 64, 2) int32
    int* out = (int*)d_out;                      // 24 int32 counters

    hipMemsetAsync(out, 0, out_size * sizeof(int), stream);
    acc_kernel<<<NBLOCKS, 256, 0, stream>>>(pred, ev, em, out);
}